// Round 8
// baseline (191.739 us; speedup 1.0000x reference)
//
#include <hip/hip_runtime.h>
#include <math.h>

#define N_ENT  15000
#define N_RELC 237
#define R2C    474
#define EBASE  200000
#define E2     400000
#define EPSV   1e-10f
#define CAP    72        // per-node edge bucket capacity (Poisson(26.7), P(>=72)~1e-11)
#define NSLICE 64
#define HITCAP 65536

typedef unsigned int uint32;
typedef unsigned short ushort16;

__device__ __forceinline__ ushort16 f2bf(float x) {
    uint32 u = __float_as_uint(x);
    u = (u + 0x7FFFu + ((u >> 16) & 1u)) >> 16;   // round-to-nearest-even
    return (ushort16)u;
}
__device__ __forceinline__ float bflo(uint32 u) { return __uint_as_float(u << 16); }
__device__ __forceinline__ float bfhi(uint32 u) { return __uint_as_float(u & 0xFFFF0000u); }
__device__ __forceinline__ uint32 pk2(float lo, float hi) {
    return (uint32)f2bf(lo) | ((uint32)f2bf(hi) << 16);
}

// ---------------------------------------------------------------------------
// init: zero out0/cursor/Swide/misc, transpose w_ih/w_hh/weight_w, and (last
// block) run prep: neg_sample_to_tail + rank-unique + inverse + head ranges.
// idx ranges: 480000 out0-f4 | 3750 cursor-i4 | 6144 Swide-f4 | 2 misc-i4
//             | 65536 wit/wht | 65536 wwt   (total 620968)
// ---------------------------------------------------------------------------
__global__ void init_kernel(float* __restrict__ out0, int* __restrict__ cursor,
                            float* __restrict__ Swide, int* __restrict__ misc,
                            const float* __restrict__ w_ih, const float* __restrict__ w_hh,
                            const float* __restrict__ weight_w,
                            float* __restrict__ wit, float* __restrict__ wht,
                            float* __restrict__ wwt,
                            const int* __restrict__ h_index, const int* __restrict__ t_index,
                            const int* __restrict__ r_index,
                            int* __restrict__ h_set, int* __restrict__ r_set,
                            int* __restrict__ invp, int* __restrict__ t_flat,
                            int* __restrict__ headidx) {
    if (blockIdx.x == gridDim.x - 1) {
        __shared__ int sv[128], eq[128], f_[128], uniq[128], hsh[128];
        __shared__ int isneg[8];
        __shared__ int UcntS;
        int j = threadIdx.x;
        for (int idx = j; idx < N_ENT; idx += 256) headidx[idx] = -1;
        __syncthreads();
        int hrv = 0, first = 0, rank = 0;
        if (j < 128) {
            int b = j >> 4;
            eq[j] = (h_index[j] == h_index[b * 16]) ? 1 : 0;
        }
        __syncthreads();
        if (j < 128 && (j & 15) == 0) {
            int b = j >> 4, a = 1;
            for (int q = 0; q < 16; q++) a &= eq[b * 16 + q];
            isneg[b] = a;
        }
        __syncthreads();
        if (j < 128) {
            int b = j >> 4;
            int h = h_index[j], t = t_index[j], r = r_index[j];
            int hi, ti, ri;
            if (isneg[b]) { hi = h; ti = t; ri = r; }
            else          { hi = t; ti = h; ri = r + N_RELC; }
            t_flat[j] = ti;
            hrv = hi * R2C + ri;
            sv[j] = hrv;
            uniq[j] = 0;
        }
        __syncthreads();
        if (j < 128) {
            first = 1;
            for (int q = 0; q < j; q++) if (sv[q] == hrv) { first = 0; break; }
            f_[j] = first;
        }
        __syncthreads();
        if (j < 128) {
            for (int q = 0; q < 128; q++) rank += (f_[q] && sv[q] < hrv) ? 1 : 0;
        }
        if (j == 0) {
            int c = 0;
            for (int q = 0; q < 128; q++) c += f_[q];
            UcntS = c;
        }
        __syncthreads();
        if (j < 128) {
            if (first) uniq[rank] = hrv;
            invp[j] = rank;
        }
        __syncthreads();
        if (j < 128) {
            int uv = uniq[j];
            h_set[j] = uv / R2C;
            r_set[j] = uv % R2C;
            hsh[j] = uv / R2C;
        }
        __syncthreads();
        if (j < 128) {
            int U = UcntS;
            int hs = hsh[j];
            if (j < U && (j == 0 || hsh[j - 1] != hs)) {
                int e = j + 1;
                while (e < U && hsh[e] == hs) e++;
                headidx[hs] = (j << 8) | e;
            }
        }
        return;
    }
    int idx = blockIdx.x * 256 + threadIdx.x;
    float4 z4 = make_float4(0.f, 0.f, 0.f, 0.f);
    if (idx < 480000) { ((float4*)out0)[idx] = z4; return; }
    idx -= 480000;
    if (idx < 3750) { ((int4*)cursor)[idx] = make_int4(0, 0, 0, 0); return; }
    idx -= 3750;
    if (idx < 6144) { ((float4*)Swide)[idx] = z4; return; }
    idx -= 6144;
    if (idx < 2) { ((int4*)misc)[idx] = make_int4(0, 0, 0, 0); return; }
    idx -= 2;
    if (idx < 65536) {
        int d = idx >> 9, g = idx & 511;
        wit[idx] = w_ih[g * 128 + d];
        wht[idx] = w_hh[g * 128 + d];
        return;
    }
    idx -= 65536;
    if (idx < 65536) {
        int d = idx >> 9, r = idx & 511;
        if (r < R2C) wwt[idx] = weight_w[r * 128 + d];
    }
}

// ---------------------------------------------------------------------------
// LSTM, all 3 steps. grid=128 (one block per query b), block=512 (gate g).
// wht staged once into LDS as bf16 (d-pairs packed per u32) -> recurrence is
// LDS-only (no global latency). x-parts (no recurrence) stream wit f32.
// ---------------------------------------------------------------------------
__global__ void lstm_kernel(const float* __restrict__ query_emb,
                            const int* __restrict__ r_set,
                            const float* __restrict__ wit, const float* __restrict__ wht,
                            const float* __restrict__ b_ih, const float* __restrict__ b_hh,
                            float* __restrict__ hidden) {
    __shared__ uint32 wl[32768];              // 128 KB: [dpair][g] bf16x2
    __shared__ float x[128], h[128], gl[512];
    int b = blockIdx.x, g = threadIdx.x;
    // stage wht -> LDS bf16 (coalesced; two strided f32 reads per u32)
    for (int i = g; i < 32768; i += 512) {
        int dd = i >> 9, gg = i & 511;
        float lo = wht[(2 * dd) * 512 + gg];
        float hi = wht[(2 * dd + 1) * 512 + gg];
        wl[i] = pk2(lo, hi);
    }
    float bias = b_ih[g] + b_hh[g];
    if (g < 128) x[g] = query_emb[r_set[b] * 128 + g];
    __syncthreads();
    float p0 = 0.f, p1 = 0.f, p2 = 0.f, p3 = 0.f;
    #pragma unroll 8
    for (int d = 0; d < 128; d += 4) {
        p0 += x[d + 0] * wit[(d + 0) * 512 + g];
        p1 += x[d + 1] * wit[(d + 1) * 512 + g];
        p2 += x[d + 2] * wit[(d + 2) * 512 + g];
        p3 += x[d + 3] * wit[(d + 3) * 512 + g];
    }
    float xpA = bias + ((p0 + p1) + (p2 + p3));
    __syncthreads();
    if (g < 128) x[g] = query_emb[R2C * 128 + g];
    __syncthreads();
    p0 = p1 = p2 = p3 = 0.f;
    #pragma unroll 8
    for (int d = 0; d < 128; d += 4) {
        p0 += x[d + 0] * wit[(d + 0) * 512 + g];
        p1 += x[d + 1] * wit[(d + 1) * 512 + g];
        p2 += x[d + 2] * wit[(d + 2) * 512 + g];
        p3 += x[d + 3] * wit[(d + 3) * 512 + g];
    }
    float xpB = bias + ((p0 + p1) + (p2 + p3));
    if (g < 128) h[g] = 0.f;
    float c = 0.f;
    __syncthreads();                          // h ready; wl staged
    for (int step = 0; step < 3; step++) {
        float a0 = 0.f, a1 = 0.f, a2 = 0.f, a3 = 0.f;
        #pragma unroll 8
        for (int dd = 0; dd < 64; dd += 2) {
            uint32 wA = wl[dd * 512 + g];
            uint32 wB = wl[(dd + 1) * 512 + g];
            a0 += h[2 * dd + 0] * bflo(wA);
            a1 += h[2 * dd + 1] * bfhi(wA);
            a2 += h[2 * dd + 2] * bflo(wB);
            a3 += h[2 * dd + 3] * bfhi(wB);
        }
        gl[g] = ((step < 2) ? xpA : xpB) + ((a0 + a1) + (a2 + a3));
        __syncthreads();
        if (g < 128) {
            float ig = gl[g], fg = gl[128 + g], gg = gl[256 + g], og = gl[384 + g];
            float si = 1.f / (1.f + expf(-ig));
            float sf = 1.f / (1.f + expf(-fg));
            float so = 1.f / (1.f + expf(-og));
            c = sf * c + si * tanhf(gg);
            float hh = so * tanhf(c);
            hidden[(step * 128 + b) * 128 + g] = hh;
            h[g] = hh;
        }
        __syncthreads();
    }
}

// ---------------------------------------------------------------------------
// fill: bucketed adjacency (cursor = degree counter) + step-0 hitlist.
// ---------------------------------------------------------------------------
__global__ void fill_kernel(const int* __restrict__ src, const int* __restrict__ dst,
                            const int* __restrict__ rel, const float* __restrict__ ew,
                            const int* __restrict__ headidx,
                            int* __restrict__ cursor, int2* __restrict__ edata2,
                            int* __restrict__ hitcnt, int4* __restrict__ hitlist) {
    int e = blockIdx.x * 256 + threadIdx.x;
    if (e >= E2) return;
    int ni, no, r;
    if (e < EBASE) { ni = src[e]; no = dst[e]; r = rel[e]; }
    else { int e2 = e - EBASE; ni = dst[e2]; no = src[e2]; r = rel[e2] + N_RELC; }
    float w = ew[e];
    int pos = atomicAdd(&cursor[no], 1);
    if (pos < CAP)
        edata2[no * CAP + pos] = make_int2((ni << 9) | r, __float_as_int(w));
    int hv = headidx[ni];
    if (hv >= 0) {
        int p = atomicAdd(hitcnt, 1);
        if (p < HITCAP) hitlist[p] = make_int4(no, r, hv, __float_as_int(w));
    }
}

// ---------------------------------------------------------------------------
// Fused attention + relation softmax (bf16 out) + normalization folding.
// ---------------------------------------------------------------------------
__global__ void coef_kernel(const float* __restrict__ hidden, int step,
                            const float* __restrict__ Swide,
                            const float* __restrict__ wwt,
                            const float* __restrict__ weight_b,
                            ushort16* __restrict__ wTb, float* __restrict__ attnS) {
    int b = blockIdx.x, tid = threadIdx.x;
    __shared__ float k[128];
    __shared__ float red[256];
    __shared__ float sc[3];
    __shared__ float Ssum[2];
    __shared__ float logit[R2C];
    if (tid < 128) k[tid] = hidden[(step * 128 + b) * 128 + tid];
    __syncthreads();
    for (int t = 0; t <= step; t++) {
        float v = 0.f;
        if (tid < 128) v = k[tid] * hidden[(t * 128 + b) * 128 + tid];
        red[tid] = v;
        __syncthreads();
        for (int s2 = 128; s2 > 0; s2 >>= 1) {
            if (tid < s2) red[tid] += red[tid + s2];
            __syncthreads();
        }
        if (tid == 0) sc[t] = red[0];
        __syncthreads();
    }
    for (int t = 0; t < step; t++) {
        red[tid] = (tid < NSLICE) ? Swide[t * (NSLICE * 128) + tid * 128 + b] : 0.f;
        __syncthreads();
        for (int s2 = 128; s2 > 0; s2 >>= 1) {
            if (tid < s2) red[tid] += red[tid + s2];
            __syncthreads();
        }
        if (tid == 0) Ssum[t] = red[0];
        __syncthreads();
    }
    if (tid == 0) {
        float m = sc[0];
        for (int t2 = 1; t2 <= step; t2++) m = fmaxf(m, sc[t2]);
        float ssum = 0.f;
        float ex[3];
        for (int t2 = 0; t2 <= step; t2++) { ex[t2] = expf(sc[t2] - m); ssum += ex[t2]; }
        for (int t2 = 0; t2 <= step; t2++) {
            float a = ex[t2] / ssum;
            if (t2 > 0) a /= fmaxf(Ssum[t2 - 1], EPSV);
            attnS[b * 4 + t2] = a;
        }
    }
    for (int r = tid; r < R2C; r += 256) {
        float acc = weight_b[r];
        #pragma unroll 8
        for (int d = 0; d < 128; d++) acc += k[d] * wwt[d * 512 + r];
        logit[r] = acc;
    }
    __syncthreads();
    float m = -1e30f;
    for (int r = tid; r < R2C; r += 256) m = fmaxf(m, logit[r]);
    red[tid] = m; __syncthreads();
    for (int s2 = 128; s2 > 0; s2 >>= 1) {
        if (tid < s2) red[tid] = fmaxf(red[tid], red[tid + s2]);
        __syncthreads();
    }
    m = red[0]; __syncthreads();
    float s = 0.f;
    for (int r = tid; r < R2C; r += 256) s += expf(logit[r] - m);
    red[tid] = s; __syncthreads();
    for (int s2 = 128; s2 > 0; s2 >>= 1) {
        if (tid < s2) red[tid] += red[tid + s2];
        __syncthreads();
    }
    float invs = 1.f / red[0];
    for (int r = tid; r < R2C; r += 256)
        wTb[r * 128 + b] = f2bf(expf(logit[r] - m) * invs);
}

// ---------------------------------------------------------------------------
// Step 0 from hitlist: out0[no][b] += wT[r][b]*w for b in [b0,b1), + col sums.
// ---------------------------------------------------------------------------
__global__ void step0_kernel(const int4* __restrict__ hitlist,
                             const int* __restrict__ hitcnt,
                             const ushort16* __restrict__ wTb,
                             float* __restrict__ out0, float* __restrict__ Sw0) {
    int idx = blockIdx.x * 256 + threadIdx.x;
    int cnt = *hitcnt;
    if (cnt > HITCAP) cnt = HITCAP;
    if (idx >= cnt) return;
    int4 hv = hitlist[idx];
    int no = hv.x, r = hv.y, b0 = hv.z >> 8, b1 = hv.z & 255;
    float w = __int_as_float(hv.w);
    int sl = (idx & (NSLICE - 1)) * 128;
    for (int b = b0; b < b1; b++) {
        float v = __uint_as_float(((uint32)wTb[r * 128 + b]) << 16) * w;
        atomicAdd(&out0[no * 128 + b], v);
        atomicAdd(&Sw0[sl + b], v);
    }
}

// ---------------------------------------------------------------------------
// inp_b16[n][b] = bf16( a0*(n==hs[b]) + a1'*o1[n][b] (+ a2'*bf16(o2b[n][b])) )
// ---------------------------------------------------------------------------
__global__ void inp_kernel(const float* __restrict__ o1, const ushort16* __restrict__ o2b,
                           int step, const float* __restrict__ attnS,
                           const int* __restrict__ h_set, ushort16* __restrict__ inpb) {
    int b = threadIdx.x;
    float a0 = attnS[b * 4 + 0];
    float a1 = attnS[b * 4 + 1];
    float a2 = (step >= 2) ? attnS[b * 4 + 2] : 0.f;
    int hs = h_set[b];
    for (int n = blockIdx.x; n < N_ENT; n += gridDim.x) {
        float v = (n == hs) ? a0 : 0.f;
        v += a1 * o1[n * 128 + b];
        if (step >= 2) v += a2 * __uint_as_float(((uint32)o2b[n * 128 + b]) << 16);
        inpb[n * 128 + b] = f2bf(v);
    }
}

// ---------------------------------------------------------------------------
// Gather (round-4 proven structure): one wave per node, lane = 2 columns
// (uint32 bf16x2 loads), broadcast edge records, 4x unroll (8 independent row
// loads in flight), fused column sums. MODE 0: bf16 out. MODE 1: f32 out.
// ---------------------------------------------------------------------------
template<int MODE>
__global__ void gather_kernel(const int2* __restrict__ edata2,
                              const int* __restrict__ cursor,
                              const ushort16* __restrict__ inpb,
                              const ushort16* __restrict__ wTb,
                              float* __restrict__ outf, ushort16* __restrict__ outb,
                              float* __restrict__ Sw) {
    __shared__ float sred[4][128];
    int wid = threadIdx.x >> 6;
    int lane = threadIdx.x & 63;
    int n = blockIdx.x * 4 + wid;                  // grid*4 == N_ENT exactly
    int deg = cursor[n];
    if (deg > CAP) deg = CAP;
    const int2* ed = edata2 + n * CAP;
    int c2 = lane * 2;
    float ax = 0.f, ay = 0.f;
    int e = 0;
    for (; e + 4 <= deg; e += 4) {
        int2 d0 = ed[e + 0], d1 = ed[e + 1], d2 = ed[e + 2], d3 = ed[e + 3];
        uint32 i0 = *(const uint32*)(inpb + ((d0.x >> 9) << 7) + c2);
        uint32 w0 = *(const uint32*)(wTb  + ((d0.x & 511) << 7) + c2);
        uint32 i1 = *(const uint32*)(inpb + ((d1.x >> 9) << 7) + c2);
        uint32 w1 = *(const uint32*)(wTb  + ((d1.x & 511) << 7) + c2);
        uint32 i2 = *(const uint32*)(inpb + ((d2.x >> 9) << 7) + c2);
        uint32 w2 = *(const uint32*)(wTb  + ((d2.x & 511) << 7) + c2);
        uint32 i3 = *(const uint32*)(inpb + ((d3.x >> 9) << 7) + c2);
        uint32 w3 = *(const uint32*)(wTb  + ((d3.x & 511) << 7) + c2);
        float f0 = __int_as_float(d0.y), f1 = __int_as_float(d1.y);
        float f2 = __int_as_float(d2.y), f3 = __int_as_float(d3.y);
        ax += bflo(i0) * bflo(w0) * f0 + bflo(i1) * bflo(w1) * f1
            + bflo(i2) * bflo(w2) * f2 + bflo(i3) * bflo(w3) * f3;
        ay += bfhi(i0) * bfhi(w0) * f0 + bfhi(i1) * bfhi(w1) * f1
            + bfhi(i2) * bfhi(w2) * f2 + bfhi(i3) * bfhi(w3) * f3;
    }
    for (; e < deg; e++) {
        int2 edv = ed[e];
        float w = __int_as_float(edv.y);
        uint32 ia = *(const uint32*)(inpb + ((edv.x >> 9) << 7) + c2);
        uint32 wa = *(const uint32*)(wTb  + ((edv.x & 511) << 7) + c2);
        ax += bflo(ia) * bflo(wa) * w;
        ay += bfhi(ia) * bfhi(wa) * w;
    }
    if (MODE == 0) {
        *(uint32*)((ushort16*)outb + (n << 7) + c2) = pk2(ax, ay);
    } else {
        *(float2*)(outf + n * 128 + c2) = make_float2(ax, ay);
    }
    sred[wid][c2] = ax;
    sred[wid][c2 + 1] = ay;
    __syncthreads();
    if (threadIdx.x < 128) {
        float s = sred[0][threadIdx.x] + sred[1][threadIdx.x]
                + sred[2][threadIdx.x] + sred[3][threadIdx.x];
        atomicAdd(&Sw[(blockIdx.x & (NSLICE - 1)) * 128 + threadIdx.x], s);
    }
}

// score[j] = (out2[t_flat[j]][inv[j]] / max(S2, EPS)) * lin_w + lin_b
__global__ void score_kernel(const float* __restrict__ out2, const float* __restrict__ Swide,
                             const int* __restrict__ t_flat, const int* __restrict__ invp,
                             const float* __restrict__ lin_w, const float* __restrict__ lin_b,
                             float* __restrict__ d_out) {
    int j = threadIdx.x;
    int bb = invp[j];
    float s = 0.f;
    for (int sl = 0; sl < NSLICE; sl++)
        s += Swide[2 * (NSLICE * 128) + sl * 128 + bb];
    d_out[j] = out2[t_flat[j] * 128 + bb] / fmaxf(s, EPSV) * lin_w[0] + lin_b[0];
}

// ---------------------------------------------------------------------------
extern "C" void kernel_launch(void* const* d_in, const int* in_sizes, int n_in,
                              void* d_out, int out_size, void* d_ws, size_t ws_size,
                              hipStream_t stream) {
    const float* query_emb  = (const float*)d_in[0];
    const float* w_ih       = (const float*)d_in[1];
    const float* w_hh       = (const float*)d_in[2];
    const float* b_ih       = (const float*)d_in[3];
    const float* b_hh       = (const float*)d_in[4];
    const float* weight_w   = (const float*)d_in[5];
    const float* weight_b   = (const float*)d_in[6];
    const float* lin_w      = (const float*)d_in[7];
    const float* lin_b      = (const float*)d_in[8];
    const float* edge_weight= (const float*)d_in[9];
    const int*   h_index    = (const int*)d_in[10];
    const int*   t_index    = (const int*)d_in[11];
    const int*   r_index    = (const int*)d_in[12];
    const int*   src        = (const int*)d_in[13];
    const int*   dst        = (const int*)d_in[14];
    const int*   rel        = (const int*)d_in[15];
    float* out = (float*)d_out;

    char* ws = (char*)d_ws;
    size_t off_b = 0;
    auto alloc = [&](size_t bytes) -> void* {
        void* p = ws + off_b;
        off_b = (off_b + bytes + 255) & ~(size_t)255;
        return p;
    };
    float*    hidden  = (float*)alloc(3 * 128 * 128 * sizeof(float));
    float*    attnS   = (float*)alloc(128 * 4 * sizeof(float));
    ushort16* wTb     = (ushort16*)alloc(R2C * 128 * sizeof(ushort16));
    float*    Swide   = (float*)alloc(3 * NSLICE * 128 * sizeof(float));
    float*    wit     = (float*)alloc(512 * 128 * sizeof(float));
    float*    wht     = (float*)alloc(512 * 128 * sizeof(float));
    float*    wwt     = (float*)alloc(512 * 128 * sizeof(float));
    int*      h_set   = (int*)alloc(128 * sizeof(int));
    int*      r_set   = (int*)alloc(128 * sizeof(int));
    int*      invp    = (int*)alloc(128 * sizeof(int));
    int*      t_flat  = (int*)alloc(128 * sizeof(int));
    int*      cursor  = (int*)alloc(N_ENT * sizeof(int));
    int*      headidx = (int*)alloc(N_ENT * sizeof(int));
    int*      misc    = (int*)alloc(8 * sizeof(int));          // hitcnt
    int2*     edata2  = (int2*)alloc((size_t)N_ENT * CAP * sizeof(int2));
    ushort16* inpb    = (ushort16*)alloc((size_t)N_ENT * 128 * sizeof(ushort16));
    float*    outs0   = (float*)alloc((size_t)N_ENT * 128 * sizeof(float));
    ushort16* out1b   = (ushort16*)alloc((size_t)N_ENT * 128 * sizeof(ushort16));
    int4*     hitlist = (int4*)alloc((size_t)HITCAP * sizeof(int4));
    int* hitcnt = misc;

    // worker idx total = 480000+3750+6144+2+65536+65536 = 620968 -> 2426 blocks
    init_kernel<<<2427, 256, 0, stream>>>(outs0, cursor, Swide, misc,
                                          w_ih, w_hh, weight_w, wit, wht, wwt,
                                          h_index, t_index, r_index,
                                          h_set, r_set, invp, t_flat, headidx);
    lstm_kernel<<<128, 512, 0, stream>>>(query_emb, r_set, wit, wht, b_ih, b_hh, hidden);
    fill_kernel<<<(E2 + 255) / 256, 256, 0, stream>>>(src, dst, rel, edge_weight,
                                                      headidx, cursor, edata2,
                                                      hitcnt, hitlist);

    // ---- step 0 ----
    coef_kernel<<<128, 256, 0, stream>>>(hidden, 0, Swide, wwt, weight_b, wTb, attnS);
    step0_kernel<<<HITCAP / 256, 256, 0, stream>>>(hitlist, hitcnt, wTb, outs0, Swide);

    // ---- step 1 (bf16 out) ----
    coef_kernel<<<128, 256, 0, stream>>>(hidden, 1, Swide, wwt, weight_b, wTb, attnS);
    inp_kernel<<<2048, 128, 0, stream>>>(outs0, out1b, 1, attnS, h_set, inpb);
    gather_kernel<0><<<N_ENT / 4, 256, 0, stream>>>(edata2, cursor, inpb, wTb,
                                                    nullptr, out1b, Swide + NSLICE * 128);

    // ---- step 2 (f32 out into outs0) ----
    coef_kernel<<<128, 256, 0, stream>>>(hidden, 2, Swide, wwt, weight_b, wTb, attnS);
    inp_kernel<<<2048, 128, 0, stream>>>(outs0, out1b, 2, attnS, h_set, inpb);
    gather_kernel<1><<<N_ENT / 4, 256, 0, stream>>>(edata2, cursor, inpb, wTb,
                                                    outs0, nullptr, Swide + 2 * NSLICE * 128);

    score_kernel<<<1, 128, 0, stream>>>(outs0, Swide, t_flat, invp, lin_w, lin_b, out);
}

// Round 9
// 190.255 us; speedup vs baseline: 1.0078x; 1.0078x over previous
//
#include <hip/hip_runtime.h>
#include <math.h>

#define N_ENT  15000
#define N_RELC 237
#define R2C    474
#define EBASE  200000
#define E2     400000
#define EPSV   1e-10f
#define CAP    72        // per-node edge bucket capacity (Poisson(26.7), P(>=72)~1e-11)
#define NSLICE 64
#define HITCAP 65536

typedef unsigned int uint32;
typedef unsigned short ushort16;

__device__ __forceinline__ ushort16 f2bf(float x) {
    uint32 u = __float_as_uint(x);
    u = (u + 0x7FFFu + ((u >> 16) & 1u)) >> 16;   // round-to-nearest-even
    return (ushort16)u;
}
__device__ __forceinline__ float bflo(uint32 u) { return __uint_as_float(u << 16); }
__device__ __forceinline__ float bfhi(uint32 u) { return __uint_as_float(u & 0xFFFF0000u); }
__device__ __forceinline__ uint32 pk2(float lo, float hi) {
    return (uint32)f2bf(lo) | ((uint32)f2bf(hi) << 16);
}

// ---------------------------------------------------------------------------
// init: zero out0/cursor/Swide/misc, transpose w_ih/w_hh/weight_w, and (last
// block) run prep: neg_sample_to_tail + rank-unique + inverse + head ranges.
// idx ranges: 480000 out0-f4 | 3750 cursor-i4 | 6144 Swide-f4 | 2 misc-i4
//             | 65536 wit/wht | 65536 wwt   (total 620968)
// ---------------------------------------------------------------------------
__global__ void init_kernel(float* __restrict__ out0, int* __restrict__ cursor,
                            float* __restrict__ Swide, int* __restrict__ misc,
                            const float* __restrict__ w_ih, const float* __restrict__ w_hh,
                            const float* __restrict__ weight_w,
                            float* __restrict__ wit, float* __restrict__ wht,
                            float* __restrict__ wwt,
                            const int* __restrict__ h_index, const int* __restrict__ t_index,
                            const int* __restrict__ r_index,
                            int* __restrict__ h_set, int* __restrict__ r_set,
                            int* __restrict__ invp, int* __restrict__ t_flat,
                            int* __restrict__ headidx) {
    if (blockIdx.x == gridDim.x - 1) {
        __shared__ int sv[128], eq[128], f_[128], uniq[128], hsh[128];
        __shared__ int isneg[8];
        __shared__ int UcntS;
        int j = threadIdx.x;
        for (int idx = j; idx < N_ENT; idx += 256) headidx[idx] = -1;
        __syncthreads();
        int hrv = 0, first = 0, rank = 0;
        if (j < 128) {
            int b = j >> 4;
            eq[j] = (h_index[j] == h_index[b * 16]) ? 1 : 0;
        }
        __syncthreads();
        if (j < 128 && (j & 15) == 0) {
            int b = j >> 4, a = 1;
            for (int q = 0; q < 16; q++) a &= eq[b * 16 + q];
            isneg[b] = a;
        }
        __syncthreads();
        if (j < 128) {
            int b = j >> 4;
            int h = h_index[j], t = t_index[j], r = r_index[j];
            int hi, ti, ri;
            if (isneg[b]) { hi = h; ti = t; ri = r; }
            else          { hi = t; ti = h; ri = r + N_RELC; }
            t_flat[j] = ti;
            hrv = hi * R2C + ri;
            sv[j] = hrv;
            uniq[j] = 0;
        }
        __syncthreads();
        if (j < 128) {
            first = 1;
            for (int q = 0; q < j; q++) if (sv[q] == hrv) { first = 0; break; }
            f_[j] = first;
        }
        __syncthreads();
        if (j < 128) {
            for (int q = 0; q < 128; q++) rank += (f_[q] && sv[q] < hrv) ? 1 : 0;
        }
        if (j == 0) {
            int c = 0;
            for (int q = 0; q < 128; q++) c += f_[q];
            UcntS = c;
        }
        __syncthreads();
        if (j < 128) {
            if (first) uniq[rank] = hrv;
            invp[j] = rank;
        }
        __syncthreads();
        if (j < 128) {
            int uv = uniq[j];
            h_set[j] = uv / R2C;
            r_set[j] = uv % R2C;
            hsh[j] = uv / R2C;
        }
        __syncthreads();
        if (j < 128) {
            int U = UcntS;
            int hs = hsh[j];
            if (j < U && (j == 0 || hsh[j - 1] != hs)) {
                int e = j + 1;
                while (e < U && hsh[e] == hs) e++;
                headidx[hs] = (j << 8) | e;
            }
        }
        return;
    }
    int idx = blockIdx.x * 256 + threadIdx.x;
    float4 z4 = make_float4(0.f, 0.f, 0.f, 0.f);
    if (idx < 480000) { ((float4*)out0)[idx] = z4; return; }
    idx -= 480000;
    if (idx < 3750) { ((int4*)cursor)[idx] = make_int4(0, 0, 0, 0); return; }
    idx -= 3750;
    if (idx < 6144) { ((float4*)Swide)[idx] = z4; return; }
    idx -= 6144;
    if (idx < 2) { ((int4*)misc)[idx] = make_int4(0, 0, 0, 0); return; }
    idx -= 2;
    if (idx < 65536) {
        int d = idx >> 9, g = idx & 511;
        wit[idx] = w_ih[g * 128 + d];
        wht[idx] = w_hh[g * 128 + d];
        return;
    }
    idx -= 65536;
    if (idx < 65536) {
        int d = idx >> 9, r = idx & 511;
        if (r < R2C) wwt[idx] = weight_w[r * 128 + d];
    }
}

// ---------------------------------------------------------------------------
// LSTM, all 3 steps (round-5 proven global-streaming form).
// grid=128 (one block per query b), block=512 (gate output g).
// ---------------------------------------------------------------------------
__global__ void lstm_kernel(const float* __restrict__ query_emb,
                            const int* __restrict__ r_set,
                            const float* __restrict__ wit, const float* __restrict__ wht,
                            const float* __restrict__ b_ih, const float* __restrict__ b_hh,
                            float* __restrict__ hidden) {
    int b = blockIdx.x, g = threadIdx.x;
    __shared__ float x[128], h[128], gl[512];
    float bias = b_ih[g] + b_hh[g];
    if (g < 128) x[g] = query_emb[r_set[b] * 128 + g];
    __syncthreads();
    float p0 = 0.f, p1 = 0.f, p2 = 0.f, p3 = 0.f;
    #pragma unroll 8
    for (int d = 0; d < 128; d += 4) {
        p0 += x[d + 0] * wit[(d + 0) * 512 + g];
        p1 += x[d + 1] * wit[(d + 1) * 512 + g];
        p2 += x[d + 2] * wit[(d + 2) * 512 + g];
        p3 += x[d + 3] * wit[(d + 3) * 512 + g];
    }
    float xpA = bias + ((p0 + p1) + (p2 + p3));
    __syncthreads();
    if (g < 128) x[g] = query_emb[R2C * 128 + g];
    __syncthreads();
    p0 = p1 = p2 = p3 = 0.f;
    #pragma unroll 8
    for (int d = 0; d < 128; d += 4) {
        p0 += x[d + 0] * wit[(d + 0) * 512 + g];
        p1 += x[d + 1] * wit[(d + 1) * 512 + g];
        p2 += x[d + 2] * wit[(d + 2) * 512 + g];
        p3 += x[d + 3] * wit[(d + 3) * 512 + g];
    }
    float xpB = bias + ((p0 + p1) + (p2 + p3));
    if (g < 128) h[g] = 0.f;
    float c = 0.f;
    __syncthreads();
    for (int step = 0; step < 3; step++) {
        float a0 = 0.f, a1 = 0.f, a2 = 0.f, a3 = 0.f;
        #pragma unroll 8
        for (int d = 0; d < 128; d += 4) {
            a0 += h[d + 0] * wht[(d + 0) * 512 + g];
            a1 += h[d + 1] * wht[(d + 1) * 512 + g];
            a2 += h[d + 2] * wht[(d + 2) * 512 + g];
            a3 += h[d + 3] * wht[(d + 3) * 512 + g];
        }
        gl[g] = ((step < 2) ? xpA : xpB) + ((a0 + a1) + (a2 + a3));
        __syncthreads();
        if (g < 128) {
            float ig = gl[g], fg = gl[128 + g], gg = gl[256 + g], og = gl[384 + g];
            float si = 1.f / (1.f + expf(-ig));
            float sf = 1.f / (1.f + expf(-fg));
            float so = 1.f / (1.f + expf(-og));
            c = sf * c + si * tanhf(gg);
            float hh = so * tanhf(c);
            hidden[(step * 128 + b) * 128 + g] = hh;
            h[g] = hh;
        }
        __syncthreads();
    }
}

// ---------------------------------------------------------------------------
// fill: bucketed adjacency + step-0 hitlist, 4 edges per thread (4 independent
// atomic chains in flight per lane). grid = ceil(E2/4/256) blocks.
// ---------------------------------------------------------------------------
__global__ void fill_kernel(const int* __restrict__ src, const int* __restrict__ dst,
                            const int* __restrict__ rel, const float* __restrict__ ew,
                            const int* __restrict__ headidx,
                            int* __restrict__ cursor, int2* __restrict__ edata2,
                            int* __restrict__ hitcnt, int4* __restrict__ hitlist) {
    const int STR = E2 / 4;                       // 100000
    int gid = blockIdx.x * 256 + threadIdx.x;
    if (gid >= STR) return;
    int ni[4], no[4], r[4];
    float w[4];
    #pragma unroll
    for (int k = 0; k < 4; k++) {
        int e = gid + k * STR;
        if (e < EBASE) { ni[k] = src[e]; no[k] = dst[e]; r[k] = rel[e]; }
        else { int e2 = e - EBASE; ni[k] = dst[e2]; no[k] = src[e2]; r[k] = rel[e2] + N_RELC; }
        w[k] = ew[e];
    }
    int pos[4], hv[4];
    #pragma unroll
    for (int k = 0; k < 4; k++) pos[k] = atomicAdd(&cursor[no[k]], 1);
    #pragma unroll
    for (int k = 0; k < 4; k++) hv[k] = headidx[ni[k]];
    #pragma unroll
    for (int k = 0; k < 4; k++) {
        if (pos[k] < CAP)
            edata2[no[k] * CAP + pos[k]] = make_int2((ni[k] << 9) | r[k], __float_as_int(w[k]));
    }
    #pragma unroll
    for (int k = 0; k < 4; k++) {
        if (hv[k] >= 0) {
            int p = atomicAdd(hitcnt, 1);
            if (p < HITCAP) hitlist[p] = make_int4(no[k], r[k], hv[k], __float_as_int(w[k]));
        }
    }
}

// ---------------------------------------------------------------------------
// Fused attention + relation softmax (bf16 out) + normalization folding.
// ---------------------------------------------------------------------------
__global__ void coef_kernel(const float* __restrict__ hidden, int step,
                            const float* __restrict__ Swide,
                            const float* __restrict__ wwt,
                            const float* __restrict__ weight_b,
                            ushort16* __restrict__ wTb, float* __restrict__ attnS) {
    int b = blockIdx.x, tid = threadIdx.x;
    __shared__ float k[128];
    __shared__ float red[256];
    __shared__ float sc[3];
    __shared__ float Ssum[2];
    __shared__ float logit[R2C];
    if (tid < 128) k[tid] = hidden[(step * 128 + b) * 128 + tid];
    __syncthreads();
    for (int t = 0; t <= step; t++) {
        float v = 0.f;
        if (tid < 128) v = k[tid] * hidden[(t * 128 + b) * 128 + tid];
        red[tid] = v;
        __syncthreads();
        for (int s2 = 128; s2 > 0; s2 >>= 1) {
            if (tid < s2) red[tid] += red[tid + s2];
            __syncthreads();
        }
        if (tid == 0) sc[t] = red[0];
        __syncthreads();
    }
    for (int t = 0; t < step; t++) {
        red[tid] = (tid < NSLICE) ? Swide[t * (NSLICE * 128) + tid * 128 + b] : 0.f;
        __syncthreads();
        for (int s2 = 128; s2 > 0; s2 >>= 1) {
            if (tid < s2) red[tid] += red[tid + s2];
            __syncthreads();
        }
        if (tid == 0) Ssum[t] = red[0];
        __syncthreads();
    }
    if (tid == 0) {
        float m = sc[0];
        for (int t2 = 1; t2 <= step; t2++) m = fmaxf(m, sc[t2]);
        float ssum = 0.f;
        float ex[3];
        for (int t2 = 0; t2 <= step; t2++) { ex[t2] = expf(sc[t2] - m); ssum += ex[t2]; }
        for (int t2 = 0; t2 <= step; t2++) {
            float a = ex[t2] / ssum;
            if (t2 > 0) a /= fmaxf(Ssum[t2 - 1], EPSV);
            attnS[b * 4 + t2] = a;
        }
    }
    for (int r = tid; r < R2C; r += 256) {
        float acc = weight_b[r];
        #pragma unroll 8
        for (int d = 0; d < 128; d++) acc += k[d] * wwt[d * 512 + r];
        logit[r] = acc;
    }
    __syncthreads();
    float m = -1e30f;
    for (int r = tid; r < R2C; r += 256) m = fmaxf(m, logit[r]);
    red[tid] = m; __syncthreads();
    for (int s2 = 128; s2 > 0; s2 >>= 1) {
        if (tid < s2) red[tid] = fmaxf(red[tid], red[tid + s2]);
        __syncthreads();
    }
    m = red[0]; __syncthreads();
    float s = 0.f;
    for (int r = tid; r < R2C; r += 256) s += expf(logit[r] - m);
    red[tid] = s; __syncthreads();
    for (int s2 = 128; s2 > 0; s2 >>= 1) {
        if (tid < s2) red[tid] += red[tid + s2];
        __syncthreads();
    }
    float invs = 1.f / red[0];
    for (int r = tid; r < R2C; r += 256)
        wTb[r * 128 + b] = f2bf(expf(logit[r] - m) * invs);
}

// ---------------------------------------------------------------------------
// Step 0 from hitlist: out0[no][b] += wT[r][b]*w for b in [b0,b1), + col sums.
// ---------------------------------------------------------------------------
__global__ void step0_kernel(const int4* __restrict__ hitlist,
                             const int* __restrict__ hitcnt,
                             const ushort16* __restrict__ wTb,
                             float* __restrict__ out0, float* __restrict__ Sw0) {
    int idx = blockIdx.x * 256 + threadIdx.x;
    int cnt = *hitcnt;
    if (cnt > HITCAP) cnt = HITCAP;
    if (idx >= cnt) return;
    int4 hv = hitlist[idx];
    int no = hv.x, r = hv.y, b0 = hv.z >> 8, b1 = hv.z & 255;
    float w = __int_as_float(hv.w);
    int sl = (idx & (NSLICE - 1)) * 128;
    for (int b = b0; b < b1; b++) {
        float v = __uint_as_float(((uint32)wTb[r * 128 + b]) << 16) * w;
        atomicAdd(&out0[no * 128 + b], v);
        atomicAdd(&Sw0[sl + b], v);
    }
}

// ---------------------------------------------------------------------------
// inp_b16[n][b] = bf16( a0*(n==hs[b]) + a1'*o1[n][b] (+ a2'*bf16(o2b[n][b])) )
// ---------------------------------------------------------------------------
__global__ void inp_kernel(const float* __restrict__ o1, const ushort16* __restrict__ o2b,
                           int step, const float* __restrict__ attnS,
                           const int* __restrict__ h_set, ushort16* __restrict__ inpb) {
    int b = threadIdx.x;
    float a0 = attnS[b * 4 + 0];
    float a1 = attnS[b * 4 + 1];
    float a2 = (step >= 2) ? attnS[b * 4 + 2] : 0.f;
    int hs = h_set[b];
    for (int n = blockIdx.x; n < N_ENT; n += gridDim.x) {
        float v = (n == hs) ? a0 : 0.f;
        v += a1 * o1[n * 128 + b];
        if (step >= 2) v += a2 * __uint_as_float(((uint32)o2b[n * 128 + b]) << 16);
        inpb[n * 128 + b] = f2bf(v);
    }
}

// ---------------------------------------------------------------------------
// Gather (round-4 proven structure): one wave per node, lane = 2 columns
// (uint32 bf16x2 loads), broadcast edge records, 4x unroll (8 independent row
// loads in flight), fused column sums. MODE 0: bf16 out. MODE 1: f32 out.
// ---------------------------------------------------------------------------
template<int MODE>
__global__ void gather_kernel(const int2* __restrict__ edata2,
                              const int* __restrict__ cursor,
                              const ushort16* __restrict__ inpb,
                              const ushort16* __restrict__ wTb,
                              float* __restrict__ outf, ushort16* __restrict__ outb,
                              float* __restrict__ Sw) {
    __shared__ float sred[4][128];
    int wid = threadIdx.x >> 6;
    int lane = threadIdx.x & 63;
    int n = blockIdx.x * 4 + wid;                  // grid*4 == N_ENT exactly
    int deg = cursor[n];
    if (deg > CAP) deg = CAP;
    const int2* ed = edata2 + n * CAP;
    int c2 = lane * 2;
    float ax = 0.f, ay = 0.f;
    int e = 0;
    for (; e + 4 <= deg; e += 4) {
        int2 d0 = ed[e + 0], d1 = ed[e + 1], d2 = ed[e + 2], d3 = ed[e + 3];
        uint32 i0 = *(const uint32*)(inpb + ((d0.x >> 9) << 7) + c2);
        uint32 w0 = *(const uint32*)(wTb  + ((d0.x & 511) << 7) + c2);
        uint32 i1 = *(const uint32*)(inpb + ((d1.x >> 9) << 7) + c2);
        uint32 w1 = *(const uint32*)(wTb  + ((d1.x & 511) << 7) + c2);
        uint32 i2 = *(const uint32*)(inpb + ((d2.x >> 9) << 7) + c2);
        uint32 w2 = *(const uint32*)(wTb  + ((d2.x & 511) << 7) + c2);
        uint32 i3 = *(const uint32*)(inpb + ((d3.x >> 9) << 7) + c2);
        uint32 w3 = *(const uint32*)(wTb  + ((d3.x & 511) << 7) + c2);
        float f0 = __int_as_float(d0.y), f1 = __int_as_float(d1.y);
        float f2 = __int_as_float(d2.y), f3 = __int_as_float(d3.y);
        ax += bflo(i0) * bflo(w0) * f0 + bflo(i1) * bflo(w1) * f1
            + bflo(i2) * bflo(w2) * f2 + bflo(i3) * bflo(w3) * f3;
        ay += bfhi(i0) * bfhi(w0) * f0 + bfhi(i1) * bfhi(w1) * f1
            + bfhi(i2) * bfhi(w2) * f2 + bfhi(i3) * bfhi(w3) * f3;
    }
    for (; e < deg; e++) {
        int2 edv = ed[e];
        float w = __int_as_float(edv.y);
        uint32 ia = *(const uint32*)(inpb + ((edv.x >> 9) << 7) + c2);
        uint32 wa = *(const uint32*)(wTb  + ((edv.x & 511) << 7) + c2);
        ax += bflo(ia) * bflo(wa) * w;
        ay += bfhi(ia) * bfhi(wa) * w;
    }
    if (MODE == 0) {
        *(uint32*)((ushort16*)outb + (n << 7) + c2) = pk2(ax, ay);
    } else {
        *(float2*)(outf + n * 128 + c2) = make_float2(ax, ay);
    }
    sred[wid][c2] = ax;
    sred[wid][c2 + 1] = ay;
    __syncthreads();
    if (threadIdx.x < 128) {
        float s = sred[0][threadIdx.x] + sred[1][threadIdx.x]
                + sred[2][threadIdx.x] + sred[3][threadIdx.x];
        atomicAdd(&Sw[(blockIdx.x & (NSLICE - 1)) * 128 + threadIdx.x], s);
    }
}

// score[j] = (out2[t_flat[j]][inv[j]] / max(S2, EPS)) * lin_w + lin_b
__global__ void score_kernel(const float* __restrict__ out2, const float* __restrict__ Swide,
                             const int* __restrict__ t_flat, const int* __restrict__ invp,
                             const float* __restrict__ lin_w, const float* __restrict__ lin_b,
                             float* __restrict__ d_out) {
    int j = threadIdx.x;
    int bb = invp[j];
    float s = 0.f;
    for (int sl = 0; sl < NSLICE; sl++)
        s += Swide[2 * (NSLICE * 128) + sl * 128 + bb];
    d_out[j] = out2[t_flat[j] * 128 + bb] / fmaxf(s, EPSV) * lin_w[0] + lin_b[0];
}

// ---------------------------------------------------------------------------
extern "C" void kernel_launch(void* const* d_in, const int* in_sizes, int n_in,
                              void* d_out, int out_size, void* d_ws, size_t ws_size,
                              hipStream_t stream) {
    const float* query_emb  = (const float*)d_in[0];
    const float* w_ih       = (const float*)d_in[1];
    const float* w_hh       = (const float*)d_in[2];
    const float* b_ih       = (const float*)d_in[3];
    const float* b_hh       = (const float*)d_in[4];
    const float* weight_w   = (const float*)d_in[5];
    const float* weight_b   = (const float*)d_in[6];
    const float* lin_w      = (const float*)d_in[7];
    const float* lin_b      = (const float*)d_in[8];
    const float* edge_weight= (const float*)d_in[9];
    const int*   h_index    = (const int*)d_in[10];
    const int*   t_index    = (const int*)d_in[11];
    const int*   r_index    = (const int*)d_in[12];
    const int*   src        = (const int*)d_in[13];
    const int*   dst        = (const int*)d_in[14];
    const int*   rel        = (const int*)d_in[15];
    float* out = (float*)d_out;

    char* ws = (char*)d_ws;
    size_t off_b = 0;
    auto alloc = [&](size_t bytes) -> void* {
        void* p = ws + off_b;
        off_b = (off_b + bytes + 255) & ~(size_t)255;
        return p;
    };
    float*    hidden  = (float*)alloc(3 * 128 * 128 * sizeof(float));
    float*    attnS   = (float*)alloc(128 * 4 * sizeof(float));
    ushort16* wTb     = (ushort16*)alloc(R2C * 128 * sizeof(ushort16));
    float*    Swide   = (float*)alloc(3 * NSLICE * 128 * sizeof(float));
    float*    wit     = (float*)alloc(512 * 128 * sizeof(float));
    float*    wht     = (float*)alloc(512 * 128 * sizeof(float));
    float*    wwt     = (float*)alloc(512 * 128 * sizeof(float));
    int*      h_set   = (int*)alloc(128 * sizeof(int));
    int*      r_set   = (int*)alloc(128 * sizeof(int));
    int*      invp    = (int*)alloc(128 * sizeof(int));
    int*      t_flat  = (int*)alloc(128 * sizeof(int));
    int*      cursor  = (int*)alloc(N_ENT * sizeof(int));
    int*      headidx = (int*)alloc(N_ENT * sizeof(int));
    int*      misc    = (int*)alloc(8 * sizeof(int));          // hitcnt
    int2*     edata2  = (int2*)alloc((size_t)N_ENT * CAP * sizeof(int2));
    ushort16* inpb    = (ushort16*)alloc((size_t)N_ENT * 128 * sizeof(ushort16));
    float*    outs0   = (float*)alloc((size_t)N_ENT * 128 * sizeof(float));
    ushort16* out1b   = (ushort16*)alloc((size_t)N_ENT * 128 * sizeof(ushort16));
    int4*     hitlist = (int4*)alloc((size_t)HITCAP * sizeof(int4));
    int* hitcnt = misc;

    // worker idx total = 480000+3750+6144+2+65536+65536 = 620968 -> 2426 blocks
    init_kernel<<<2427, 256, 0, stream>>>(outs0, cursor, Swide, misc,
                                          w_ih, w_hh, weight_w, wit, wht, wwt,
                                          h_index, t_index, r_index,
                                          h_set, r_set, invp, t_flat, headidx);
    lstm_kernel<<<128, 512, 0, stream>>>(query_emb, r_set, wit, wht, b_ih, b_hh, hidden);
    fill_kernel<<<(E2 / 4 + 255) / 256, 256, 0, stream>>>(src, dst, rel, edge_weight,
                                                          headidx, cursor, edata2,
                                                          hitcnt, hitlist);

    // ---- step 0 ----
    coef_kernel<<<128, 256, 0, stream>>>(hidden, 0, Swide, wwt, weight_b, wTb, attnS);
    step0_kernel<<<HITCAP / 256, 256, 0, stream>>>(hitlist, hitcnt, wTb, outs0, Swide);

    // ---- step 1 (bf16 out) ----
    coef_kernel<<<128, 256, 0, stream>>>(hidden, 1, Swide, wwt, weight_b, wTb, attnS);
    inp_kernel<<<2048, 128, 0, stream>>>(outs0, out1b, 1, attnS, h_set, inpb);
    gather_kernel<0><<<N_ENT / 4, 256, 0, stream>>>(edata2, cursor, inpb, wTb,
                                                    nullptr, out1b, Swide + NSLICE * 128);

    // ---- step 2 (f32 out into outs0) ----
    coef_kernel<<<128, 256, 0, stream>>>(hidden, 2, Swide, wwt, weight_b, wTb, attnS);
    inp_kernel<<<2048, 128, 0, stream>>>(outs0, out1b, 2, attnS, h_set, inpb);
    gather_kernel<1><<<N_ENT / 4, 256, 0, stream>>>(edata2, cursor, inpb, wTb,
                                                    outs0, nullptr, Swide + 2 * NSLICE * 128);

    score_kernel<<<1, 128, 0, stream>>>(outs0, Swide, t_flat, invp, lin_w, lin_b, out);
}

// Round 10
// 166.826 us; speedup vs baseline: 1.1493x; 1.1404x over previous
//
#include <hip/hip_runtime.h>
#include <math.h>

#define N_ENT  15000
#define N_RELC 237
#define R2C    474
#define EBASE  200000
#define E2     400000
#define EPSV   1e-10f
#define CAP    72        // per-node edge bucket capacity (Poisson(26.7), P(>=72)~1e-11)
#define NSLICE 64
#define CSTR   16        // cursor stride: one counter per 64B line

typedef unsigned int uint32;
typedef unsigned short ushort16;

__device__ __forceinline__ ushort16 f2bf(float x) {
    uint32 u = __float_as_uint(x);
    u = (u + 0x7FFFu + ((u >> 16) & 1u)) >> 16;   // round-to-nearest-even
    return (ushort16)u;
}
__device__ __forceinline__ float bflo(uint32 u) { return __uint_as_float(u << 16); }
__device__ __forceinline__ float bfhi(uint32 u) { return __uint_as_float(u & 0xFFFF0000u); }
__device__ __forceinline__ uint32 pk2(float lo, float hi) {
    return (uint32)f2bf(lo) | ((uint32)f2bf(hi) << 16);
}

// ---------------------------------------------------------------------------
// init: zero out0/cursor/Swide, transpose w_ih/w_hh/weight_w, and (last block)
// run prep: neg_sample_to_tail + rank-unique + inverse + head ranges.
// idx ranges (256-thr blocks): 480000 out0-f4 | 60000 cursor-i4 | 6144 Swide-f4
//                              | 65536 wit/wht | 65536 wwt  (total 677216)
// ---------------------------------------------------------------------------
__global__ void init_kernel(float* __restrict__ out0, int* __restrict__ cursor,
                            float* __restrict__ Swide,
                            const float* __restrict__ w_ih, const float* __restrict__ w_hh,
                            const float* __restrict__ weight_w,
                            float* __restrict__ wit, float* __restrict__ wht,
                            float* __restrict__ wwt,
                            const int* __restrict__ h_index, const int* __restrict__ t_index,
                            const int* __restrict__ r_index,
                            int* __restrict__ h_set, int* __restrict__ r_set,
                            int* __restrict__ invp, int* __restrict__ t_flat,
                            int* __restrict__ headidx) {
    if (blockIdx.x == gridDim.x - 1) {
        __shared__ int sv[128], eq[128], f_[128], uniq[128], hsh[128];
        __shared__ int isneg[8];
        __shared__ int UcntS;
        int j = threadIdx.x;
        for (int idx = j; idx < N_ENT; idx += 256) headidx[idx] = -1;
        __syncthreads();
        int hrv = 0, first = 0, rank = 0;
        if (j < 128) {
            int b = j >> 4;
            eq[j] = (h_index[j] == h_index[b * 16]) ? 1 : 0;
        }
        __syncthreads();
        if (j < 128 && (j & 15) == 0) {
            int b = j >> 4, a = 1;
            for (int q = 0; q < 16; q++) a &= eq[b * 16 + q];
            isneg[b] = a;
        }
        __syncthreads();
        if (j < 128) {
            int b = j >> 4;
            int h = h_index[j], t = t_index[j], r = r_index[j];
            int hi, ti, ri;
            if (isneg[b]) { hi = h; ti = t; ri = r; }
            else          { hi = t; ti = h; ri = r + N_RELC; }
            t_flat[j] = ti;
            hrv = hi * R2C + ri;
            sv[j] = hrv;
            uniq[j] = 0;
        }
        __syncthreads();
        if (j < 128) {
            first = 1;
            for (int q = 0; q < j; q++) if (sv[q] == hrv) { first = 0; break; }
            f_[j] = first;
        }
        __syncthreads();
        if (j < 128) {
            for (int q = 0; q < 128; q++) rank += (f_[q] && sv[q] < hrv) ? 1 : 0;
        }
        if (j == 0) {
            int c = 0;
            for (int q = 0; q < 128; q++) c += f_[q];
            UcntS = c;
        }
        __syncthreads();
        if (j < 128) {
            if (first) uniq[rank] = hrv;
            invp[j] = rank;
        }
        __syncthreads();
        if (j < 128) {
            int uv = uniq[j];
            h_set[j] = uv / R2C;
            r_set[j] = uv % R2C;
            hsh[j] = uv / R2C;
        }
        __syncthreads();
        if (j < 128) {
            int U = UcntS;
            int hs = hsh[j];
            if (j < U && (j == 0 || hsh[j - 1] != hs)) {
                int e = j + 1;
                while (e < U && hsh[e] == hs) e++;
                headidx[hs] = (j << 8) | e;
            }
        }
        return;
    }
    int idx = blockIdx.x * 256 + threadIdx.x;
    float4 z4 = make_float4(0.f, 0.f, 0.f, 0.f);
    if (idx < 480000) { ((float4*)out0)[idx] = z4; return; }
    idx -= 480000;
    if (idx < 60000) { ((int4*)cursor)[idx] = make_int4(0, 0, 0, 0); return; }
    idx -= 60000;
    if (idx < 6144) { ((float4*)Swide)[idx] = z4; return; }
    idx -= 6144;
    if (idx < 65536) {
        int d = idx >> 9, g = idx & 511;
        wit[idx] = w_ih[g * 128 + d];
        wht[idx] = w_hh[g * 128 + d];
        return;
    }
    idx -= 65536;
    if (idx < 65536) {
        int d = idx >> 9, r = idx & 511;
        if (r < R2C) wwt[idx] = weight_w[r * 128 + d];
    }
}

// ---------------------------------------------------------------------------
// LSTM, all 3 steps (proven global-streaming form).
// grid=128 (one block per query b), block=512 (gate output g).
// ---------------------------------------------------------------------------
__global__ void lstm_kernel(const float* __restrict__ query_emb,
                            const int* __restrict__ r_set,
                            const float* __restrict__ wit, const float* __restrict__ wht,
                            const float* __restrict__ b_ih, const float* __restrict__ b_hh,
                            float* __restrict__ hidden) {
    int b = blockIdx.x, g = threadIdx.x;
    __shared__ float x[128], h[128], gl[512];
    float bias = b_ih[g] + b_hh[g];
    if (g < 128) x[g] = query_emb[r_set[b] * 128 + g];
    __syncthreads();
    float p0 = 0.f, p1 = 0.f, p2 = 0.f, p3 = 0.f;
    #pragma unroll 8
    for (int d = 0; d < 128; d += 4) {
        p0 += x[d + 0] * wit[(d + 0) * 512 + g];
        p1 += x[d + 1] * wit[(d + 1) * 512 + g];
        p2 += x[d + 2] * wit[(d + 2) * 512 + g];
        p3 += x[d + 3] * wit[(d + 3) * 512 + g];
    }
    float xpA = bias + ((p0 + p1) + (p2 + p3));
    __syncthreads();
    if (g < 128) x[g] = query_emb[R2C * 128 + g];
    __syncthreads();
    p0 = p1 = p2 = p3 = 0.f;
    #pragma unroll 8
    for (int d = 0; d < 128; d += 4) {
        p0 += x[d + 0] * wit[(d + 0) * 512 + g];
        p1 += x[d + 1] * wit[(d + 1) * 512 + g];
        p2 += x[d + 2] * wit[(d + 2) * 512 + g];
        p3 += x[d + 3] * wit[(d + 3) * 512 + g];
    }
    float xpB = bias + ((p0 + p1) + (p2 + p3));
    if (g < 128) h[g] = 0.f;
    float c = 0.f;
    __syncthreads();
    for (int step = 0; step < 3; step++) {
        float a0 = 0.f, a1 = 0.f, a2 = 0.f, a3 = 0.f;
        #pragma unroll 8
        for (int d = 0; d < 128; d += 4) {
            a0 += h[d + 0] * wht[(d + 0) * 512 + g];
            a1 += h[d + 1] * wht[(d + 1) * 512 + g];
            a2 += h[d + 2] * wht[(d + 2) * 512 + g];
            a3 += h[d + 3] * wht[(d + 3) * 512 + g];
        }
        gl[g] = ((step < 2) ? xpA : xpB) + ((a0 + a1) + (a2 + a3));
        __syncthreads();
        if (g < 128) {
            float ig = gl[g], fg = gl[128 + g], gg = gl[256 + g], og = gl[384 + g];
            float si = 1.f / (1.f + expf(-ig));
            float sf = 1.f / (1.f + expf(-fg));
            float so = 1.f / (1.f + expf(-og));
            c = sf * c + si * tanhf(gg);
            float hh = so * tanhf(c);
            hidden[(step * 128 + b) * 128 + g] = hh;
            h[g] = hh;
        }
        __syncthreads();
    }
}

// ---------------------------------------------------------------------------
// fill: bucketed adjacency; cursor padded one-counter-per-64B-line.
// ---------------------------------------------------------------------------
__global__ void fill_kernel(const int* __restrict__ src, const int* __restrict__ dst,
                            const int* __restrict__ rel, const float* __restrict__ ew,
                            int* __restrict__ cursor, int2* __restrict__ edata2) {
    int e = blockIdx.x * 256 + threadIdx.x;
    if (e >= E2) return;
    int ni, no, r;
    if (e < EBASE) { ni = src[e]; no = dst[e]; r = rel[e]; }
    else { int e2 = e - EBASE; ni = dst[e2]; no = src[e2]; r = rel[e2] + N_RELC; }
    float w = ew[e];
    int pos = atomicAdd(&cursor[no * CSTR], 1);
    if (pos < CAP)
        edata2[no * CAP + pos] = make_int2((ni << 9) | r, __float_as_int(w));
}

// ---------------------------------------------------------------------------
// Fused attention + relation softmax (bf16 out) + normalization folding.
// ---------------------------------------------------------------------------
__global__ void coef_kernel(const float* __restrict__ hidden, int step,
                            const float* __restrict__ Swide,
                            const float* __restrict__ wwt,
                            const float* __restrict__ weight_b,
                            ushort16* __restrict__ wTb, float* __restrict__ attnS) {
    int b = blockIdx.x, tid = threadIdx.x;
    __shared__ float k[128];
    __shared__ float red[256];
    __shared__ float sc[3];
    __shared__ float Ssum[2];
    __shared__ float logit[R2C];
    if (tid < 128) k[tid] = hidden[(step * 128 + b) * 128 + tid];
    __syncthreads();
    for (int t = 0; t <= step; t++) {
        float v = 0.f;
        if (tid < 128) v = k[tid] * hidden[(t * 128 + b) * 128 + tid];
        red[tid] = v;
        __syncthreads();
        for (int s2 = 128; s2 > 0; s2 >>= 1) {
            if (tid < s2) red[tid] += red[tid + s2];
            __syncthreads();
        }
        if (tid == 0) sc[t] = red[0];
        __syncthreads();
    }
    for (int t = 0; t < step; t++) {
        red[tid] = (tid < NSLICE) ? Swide[t * (NSLICE * 128) + tid * 128 + b] : 0.f;
        __syncthreads();
        for (int s2 = 128; s2 > 0; s2 >>= 1) {
            if (tid < s2) red[tid] += red[tid + s2];
            __syncthreads();
        }
        if (tid == 0) Ssum[t] = red[0];
        __syncthreads();
    }
    if (tid == 0) {
        float m = sc[0];
        for (int t2 = 1; t2 <= step; t2++) m = fmaxf(m, sc[t2]);
        float ssum = 0.f;
        float ex[3];
        for (int t2 = 0; t2 <= step; t2++) { ex[t2] = expf(sc[t2] - m); ssum += ex[t2]; }
        for (int t2 = 0; t2 <= step; t2++) {
            float a = ex[t2] / ssum;
            if (t2 > 0) a /= fmaxf(Ssum[t2 - 1], EPSV);
            attnS[b * 4 + t2] = a;
        }
    }
    for (int r = tid; r < R2C; r += 256) {
        float acc = weight_b[r];
        #pragma unroll 8
        for (int d = 0; d < 128; d++) acc += k[d] * wwt[d * 512 + r];
        logit[r] = acc;
    }
    __syncthreads();
    float m = -1e30f;
    for (int r = tid; r < R2C; r += 256) m = fmaxf(m, logit[r]);
    red[tid] = m; __syncthreads();
    for (int s2 = 128; s2 > 0; s2 >>= 1) {
        if (tid < s2) red[tid] = fmaxf(red[tid], red[tid + s2]);
        __syncthreads();
    }
    m = red[0]; __syncthreads();
    float s = 0.f;
    for (int r = tid; r < R2C; r += 256) s += expf(logit[r] - m);
    red[tid] = s; __syncthreads();
    for (int s2 = 128; s2 > 0; s2 >>= 1) {
        if (tid < s2) red[tid] += red[tid + s2];
        __syncthreads();
    }
    float invs = 1.f / red[0];
    for (int r = tid; r < R2C; r += 256)
        wTb[r * 128 + b] = f2bf(expf(logit[r] - m) * invs);
}

// ---------------------------------------------------------------------------
// Step 0: inp = one-hot(h_set); full scan, scatter edges whose source is a
// head node; also accumulates column sums into Swide[0] slices.
// ---------------------------------------------------------------------------
__global__ void step0_kernel(const int* __restrict__ src, const int* __restrict__ dst,
                             const int* __restrict__ rel, const float* __restrict__ ew,
                             const int* __restrict__ headidx,
                             const ushort16* __restrict__ wTb,
                             float* __restrict__ out0, float* __restrict__ Sw0) {
    int e = blockIdx.x * 256 + threadIdx.x;
    if (e >= E2) return;
    int ni, no, r;
    if (e < EBASE) { ni = src[e]; no = dst[e]; r = rel[e]; }
    else { int e2 = e - EBASE; ni = dst[e2]; no = src[e2]; r = rel[e2] + N_RELC; }
    int hv = headidx[ni];
    if (hv < 0) return;
    float w = ew[e];
    int b0 = hv >> 8, b1 = hv & 255;
    int sl = (e & (NSLICE - 1)) * 128;
    for (int b = b0; b < b1; b++) {
        float v = __uint_as_float(((uint32)wTb[r * 128 + b]) << 16) * w;
        atomicAdd(&out0[no * 128 + b], v);
        atomicAdd(&Sw0[sl + b], v);
    }
}

// ---------------------------------------------------------------------------
// inp_b16[n][b] = bf16( a0*(n==hs[b]) + a1'*o1[n][b] (+ a2'*bf16(o2b[n][b])) )
// ---------------------------------------------------------------------------
__global__ void inp_kernel(const float* __restrict__ o1, const ushort16* __restrict__ o2b,
                           int step, const float* __restrict__ attnS,
                           const int* __restrict__ h_set, ushort16* __restrict__ inpb) {
    int b = threadIdx.x;
    float a0 = attnS[b * 4 + 0];
    float a1 = attnS[b * 4 + 1];
    float a2 = (step >= 2) ? attnS[b * 4 + 2] : 0.f;
    int hs = h_set[b];
    for (int n = blockIdx.x; n < N_ENT; n += gridDim.x) {
        float v = (n == hs) ? a0 : 0.f;
        v += a1 * o1[n * 128 + b];
        if (step >= 2) v += a2 * __uint_as_float(((uint32)o2b[n * 128 + b]) << 16);
        inpb[n * 128 + b] = f2bf(v);
    }
}

// ---------------------------------------------------------------------------
// Gather (proven structure): one wave per node, lane = 2 columns (uint32
// bf16x2 loads), broadcast edge records, 4x unroll, fused column sums.
// MODE 0: bf16 out. MODE 1: f32 out.
// ---------------------------------------------------------------------------
template<int MODE>
__global__ void gather_kernel(const int2* __restrict__ edata2,
                              const int* __restrict__ cursor,
                              const ushort16* __restrict__ inpb,
                              const ushort16* __restrict__ wTb,
                              float* __restrict__ outf, ushort16* __restrict__ outb,
                              float* __restrict__ Sw) {
    __shared__ float sred[4][128];
    int wid = threadIdx.x >> 6;
    int lane = threadIdx.x & 63;
    int n = blockIdx.x * 4 + wid;                  // grid*4 == N_ENT exactly
    int deg = cursor[n * CSTR];
    if (deg > CAP) deg = CAP;
    const int2* ed = edata2 + n * CAP;
    int c2 = lane * 2;
    float ax = 0.f, ay = 0.f;
    int e = 0;
    for (; e + 4 <= deg; e += 4) {
        int2 d0 = ed[e + 0], d1 = ed[e + 1], d2 = ed[e + 2], d3 = ed[e + 3];
        uint32 i0 = *(const uint32*)(inpb + ((d0.x >> 9) << 7) + c2);
        uint32 w0 = *(const uint32*)(wTb  + ((d0.x & 511) << 7) + c2);
        uint32 i1 = *(const uint32*)(inpb + ((d1.x >> 9) << 7) + c2);
        uint32 w1 = *(const uint32*)(wTb  + ((d1.x & 511) << 7) + c2);
        uint32 i2 = *(const uint32*)(inpb + ((d2.x >> 9) << 7) + c2);
        uint32 w2 = *(const uint32*)(wTb  + ((d2.x & 511) << 7) + c2);
        uint32 i3 = *(const uint32*)(inpb + ((d3.x >> 9) << 7) + c2);
        uint32 w3 = *(const uint32*)(wTb  + ((d3.x & 511) << 7) + c2);
        float f0 = __int_as_float(d0.y), f1 = __int_as_float(d1.y);
        float f2 = __int_as_float(d2.y), f3 = __int_as_float(d3.y);
        ax += bflo(i0) * bflo(w0) * f0 + bflo(i1) * bflo(w1) * f1
            + bflo(i2) * bflo(w2) * f2 + bflo(i3) * bflo(w3) * f3;
        ay += bfhi(i0) * bfhi(w0) * f0 + bfhi(i1) * bfhi(w1) * f1
            + bfhi(i2) * bfhi(w2) * f2 + bfhi(i3) * bfhi(w3) * f3;
    }
    for (; e < deg; e++) {
        int2 edv = ed[e];
        float w = __int_as_float(edv.y);
        uint32 ia = *(const uint32*)(inpb + ((edv.x >> 9) << 7) + c2);
        uint32 wa = *(const uint32*)(wTb  + ((edv.x & 511) << 7) + c2);
        ax += bflo(ia) * bflo(wa) * w;
        ay += bfhi(ia) * bfhi(wa) * w;
    }
    if (MODE == 0) {
        *(uint32*)((ushort16*)outb + (n << 7) + c2) = pk2(ax, ay);
    } else {
        *(float2*)(outf + n * 128 + c2) = make_float2(ax, ay);
    }
    sred[wid][c2] = ax;
    sred[wid][c2 + 1] = ay;
    __syncthreads();
    if (threadIdx.x < 128) {
        float s = sred[0][threadIdx.x] + sred[1][threadIdx.x]
                + sred[2][threadIdx.x] + sred[3][threadIdx.x];
        atomicAdd(&Sw[(blockIdx.x & (NSLICE - 1)) * 128 + threadIdx.x], s);
    }
}

// score[j] = (out2[t_flat[j]][inv[j]] / max(S2, EPS)) * lin_w + lin_b
__global__ void score_kernel(const float* __restrict__ out2, const float* __restrict__ Swide,
                             const int* __restrict__ t_flat, const int* __restrict__ invp,
                             const float* __restrict__ lin_w, const float* __restrict__ lin_b,
                             float* __restrict__ d_out) {
    int j = threadIdx.x;
    int bb = invp[j];
    float s = 0.f;
    for (int sl = 0; sl < NSLICE; sl++)
        s += Swide[2 * (NSLICE * 128) + sl * 128 + bb];
    d_out[j] = out2[t_flat[j] * 128 + bb] / fmaxf(s, EPSV) * lin_w[0] + lin_b[0];
}

// ---------------------------------------------------------------------------
extern "C" void kernel_launch(void* const* d_in, const int* in_sizes, int n_in,
                              void* d_out, int out_size, void* d_ws, size_t ws_size,
                              hipStream_t stream) {
    const float* query_emb  = (const float*)d_in[0];
    const float* w_ih       = (const float*)d_in[1];
    const float* w_hh       = (const float*)d_in[2];
    const float* b_ih       = (const float*)d_in[3];
    const float* b_hh       = (const float*)d_in[4];
    const float* weight_w   = (const float*)d_in[5];
    const float* weight_b   = (const float*)d_in[6];
    const float* lin_w      = (const float*)d_in[7];
    const float* lin_b      = (const float*)d_in[8];
    const float* edge_weight= (const float*)d_in[9];
    const int*   h_index    = (const int*)d_in[10];
    const int*   t_index    = (const int*)d_in[11];
    const int*   r_index    = (const int*)d_in[12];
    const int*   src        = (const int*)d_in[13];
    const int*   dst        = (const int*)d_in[14];
    const int*   rel        = (const int*)d_in[15];
    float* out = (float*)d_out;

    char* ws = (char*)d_ws;
    size_t off_b = 0;
    auto alloc = [&](size_t bytes) -> void* {
        void* p = ws + off_b;
        off_b = (off_b + bytes + 255) & ~(size_t)255;
        return p;
    };
    float*    hidden  = (float*)alloc(3 * 128 * 128 * sizeof(float));
    float*    attnS   = (float*)alloc(128 * 4 * sizeof(float));
    ushort16* wTb     = (ushort16*)alloc(R2C * 128 * sizeof(ushort16));
    float*    Swide   = (float*)alloc(3 * NSLICE * 128 * sizeof(float));
    float*    wit     = (float*)alloc(512 * 128 * sizeof(float));
    float*    wht     = (float*)alloc(512 * 128 * sizeof(float));
    float*    wwt     = (float*)alloc(512 * 128 * sizeof(float));
    int*      h_set   = (int*)alloc(128 * sizeof(int));
    int*      r_set   = (int*)alloc(128 * sizeof(int));
    int*      invp    = (int*)alloc(128 * sizeof(int));
    int*      t_flat  = (int*)alloc(128 * sizeof(int));
    int*      cursor  = (int*)alloc((size_t)N_ENT * CSTR * sizeof(int));
    int*      headidx = (int*)alloc(N_ENT * sizeof(int));
    int2*     edata2  = (int2*)alloc((size_t)N_ENT * CAP * sizeof(int2));
    ushort16* inpb    = (ushort16*)alloc((size_t)N_ENT * 128 * sizeof(ushort16));
    float*    outs0   = (float*)alloc((size_t)N_ENT * 128 * sizeof(float));
    ushort16* out1b   = (ushort16*)alloc((size_t)N_ENT * 128 * sizeof(ushort16));

    // worker idx total = 480000+60000+6144+65536+65536 = 677216 -> 2646 blocks
    init_kernel<<<2647, 256, 0, stream>>>(outs0, cursor, Swide,
                                          w_ih, w_hh, weight_w, wit, wht, wwt,
                                          h_index, t_index, r_index,
                                          h_set, r_set, invp, t_flat, headidx);
    lstm_kernel<<<128, 512, 0, stream>>>(query_emb, r_set, wit, wht, b_ih, b_hh, hidden);
    fill_kernel<<<(E2 + 255) / 256, 256, 0, stream>>>(src, dst, rel, edge_weight,
                                                      cursor, edata2);

    // ---- step 0 ----
    coef_kernel<<<128, 256, 0, stream>>>(hidden, 0, Swide, wwt, weight_b, wTb, attnS);
    step0_kernel<<<(E2 + 255) / 256, 256, 0, stream>>>(src, dst, rel, edge_weight,
                                                       headidx, wTb, outs0, Swide);

    // ---- step 1 (bf16 out) ----
    coef_kernel<<<128, 256, 0, stream>>>(hidden, 1, Swide, wwt, weight_b, wTb, attnS);
    inp_kernel<<<2048, 128, 0, stream>>>(outs0, out1b, 1, attnS, h_set, inpb);
    gather_kernel<0><<<N_ENT / 4, 256, 0, stream>>>(edata2, cursor, inpb, wTb,
                                                    nullptr, out1b, Swide + NSLICE * 128);

    // ---- step 2 (f32 out into outs0) ----
    coef_kernel<<<128, 256, 0, stream>>>(hidden, 2, Swide, wwt, weight_b, wTb, attnS);
    inp_kernel<<<2048, 128, 0, stream>>>(outs0, out1b, 2, attnS, h_set, inpb);
    gather_kernel<1><<<N_ENT / 4, 256, 0, stream>>>(edata2, cursor, inpb, wTb,
                                                    outs0, nullptr, Swide + 2 * NSLICE * 128);

    score_kernel<<<1, 128, 0, stream>>>(outs0, Swide, t_flat, invp, lin_w, lin_b, out);
}